// Round 4
// baseline (8473.409 us; speedup 1.0000x reference)
//
#include <hip/hip_runtime.h>
#include <hip/hip_bf16.h>
#include <cmath>

#define FPS_N 8192
#define FPS_K 4096
#define CS    256
#define FT    1024         // FPS threads (16 waves)
#define PPT   8            // points per thread
#define NEGINF (-__builtin_inff())
#define KMAX  0x7fffffff

// Minkowski-p3 "sum of |d|^3" with reference-exact f32 op order (no FMA contraction).
__device__ __forceinline__ float p3sum(float x, float y, float z,
                                       float nx, float ny, float nz) {
  float dx = fabsf(__fsub_rn(x, nx));
  float dy = fabsf(__fsub_rn(y, ny));
  float dz = fabsf(__fsub_rn(z, nz));
  float cx = __fmul_rn(__fmul_rn(dx, dx), dx);
  float cy = __fmul_rn(__fmul_rn(dy, dy), dy);
  float cz = __fmul_rn(__fmul_rn(dz, dz), dz);
  return __fadd_rn(__fadd_rn(cx, cy), cz);
}

// Squared Euclidean distance, reference-exact f32 op order.
__device__ __forceinline__ float eucl2(float x, float y, float z,
                                       float nx, float ny, float nz) {
  float dx = __fsub_rn(x, nx);
  float dy = __fsub_rn(y, ny);
  float dz = __fsub_rn(z, nz);
  return __fadd_rn(__fadd_rn(__fmul_rn(dx, dx), __fmul_rn(dy, dy)),
                   __fmul_rn(dz, dz));
}

#define LEXGT(va, ka, vb, kb) (((va) > (vb)) || ((va) == (vb) && ((ka) < (kb))))

template<int CTRL>
__device__ __forceinline__ int dppi(int a) {
  return __builtin_amdgcn_update_dpp(a, a, CTRL, 0xF, 0xF, false);
}
template<int CTRL>
__device__ __forceinline__ float dppf(float a) {
  return __int_as_float(__builtin_amdgcn_update_dpp(__float_as_int(a), __float_as_int(a), CTRL, 0xF, 0xF, false));
}

// lex-max select carrying 5-field payload (used for 16-slot extraction).
template<int CTRL>
__device__ __forceinline__ void dpp_sel7(float& v, int& k, float& x, float& y,
                                         float& z, float& v2, int& k2) {
  float pv = dppf<CTRL>(v);  int pk = dppi<CTRL>(k);
  float px = dppf<CTRL>(x);  float py = dppf<CTRL>(y);  float pz = dppf<CTRL>(z);
  float pv2 = dppf<CTRL>(v2); int pk2 = dppi<CTRL>(k2);
  bool t = LEXGT(pv, pk, v, k);
  v = t ? pv : v;   k = t ? pk : k;
  x = t ? px : x;   y = t ? py : y;   z = t ? pz : z;
  v2 = t ? pv2 : v2; k2 = t ? pk2 : k2;
}

// top-2 merge across lanes (wave reduce): keeps lex-ordered (v1,k1) >= (v2,k2).
template<int CTRL>
__device__ __forceinline__ void dpp_top2(float& v1, int& k1, float& v2, int& k2) {
  float p1 = dppf<CTRL>(v1); int q1 = dppi<CTRL>(k1);
  float p2 = dppf<CTRL>(v2); int q2 = dppi<CTRL>(k2);
  bool t = LEXGT(p1, q1, v1, k1);
  float lv = t ? v1 : p1; int lk = t ? k1 : q1;   // losing top1
  float ov = t ? p2 : v2; int ok = t ? q2 : k2;   // winning side's top2
  v1 = t ? p1 : v1; k1 = t ? q1 : k1;
  bool u = LEXGT(lv, lk, ov, ok);
  v2 = u ? lv : ov; k2 = u ? lk : ok;
}

// ---------------------------------------------------------------------------
// 12-bit Morton (16x16x16 over [-4,4]^3) counting sort. Within-cell order is
// nondeterministic (atomics) but the FPS result is invariant to it (lex keys
// carry original indices; bbox skip is conservative).
// ---------------------------------------------------------------------------
__global__ __launch_bounds__(FT) void bin_kernel(const float* __restrict__ pos,
                                                 float* __restrict__ pos_s,
                                                 int* __restrict__ ids_s) {
  __shared__ int hist[4096];
  __shared__ int part[FT];
  const int tid = threadIdx.x;
#pragma unroll
  for (int i = 0; i < 4; ++i) hist[tid * 4 + i] = 0;
  __syncthreads();

  float qx[PPT], qy[PPT], qz[PPT];
  int cell[PPT];
  {
    const float4* p4 = (const float4*)pos + tid * 6;
    float4 a0 = p4[0], a1 = p4[1], a2 = p4[2], a3 = p4[3], a4 = p4[4], a5 = p4[5];
    qx[0]=a0.x; qy[0]=a0.y; qz[0]=a0.z;
    qx[1]=a0.w; qy[1]=a1.x; qz[1]=a1.y;
    qx[2]=a1.z; qy[2]=a1.w; qz[2]=a2.x;
    qx[3]=a2.y; qy[3]=a2.z; qz[3]=a2.w;
    qx[4]=a3.x; qy[4]=a3.y; qz[4]=a3.z;
    qx[5]=a3.w; qy[5]=a4.x; qz[5]=a4.y;
    qx[6]=a4.z; qy[6]=a4.w; qz[6]=a5.x;
    qx[7]=a5.y; qy[7]=a5.z; qz[7]=a5.w;
  }
#pragma unroll
  for (int j = 0; j < PPT; ++j) {
    int ix = min(max((int)floorf((qx[j] + 4.0f) * 2.0f), 0), 15);
    int iy = min(max((int)floorf((qy[j] + 4.0f) * 2.0f), 0), 15);
    int iz = min(max((int)floorf((qz[j] + 4.0f) * 2.0f), 0), 15);
    int m = 0;
#pragma unroll
    for (int b = 0; b < 4; ++b)
      m |= (((ix >> b) & 1) << (3 * b)) | (((iy >> b) & 1) << (3 * b + 1)) |
           (((iz >> b) & 1) << (3 * b + 2));
    cell[j] = m;
    atomicAdd(&hist[m], 1);
  }
  __syncthreads();
  int h0 = hist[tid * 4], h1 = hist[tid * 4 + 1], h2 = hist[tid * 4 + 2], h3 = hist[tid * 4 + 3];
  int s = h0 + h1 + h2 + h3;
  part[tid] = s;
  __syncthreads();
  for (int off = 1; off < FT; off <<= 1) {
    int u = (tid >= off) ? part[tid - off] : 0;
    __syncthreads();
    part[tid] += u;
    __syncthreads();
  }
  int base = part[tid] - s;
  hist[tid * 4 + 0] = base;
  hist[tid * 4 + 1] = base + h0;
  hist[tid * 4 + 2] = base + h0 + h1;
  hist[tid * 4 + 3] = base + h0 + h1 + h2;
  __syncthreads();
#pragma unroll
  for (int j = 0; j < PPT; ++j) {
    int slot = atomicAdd(&hist[cell[j]], 1);
    pos_s[slot * 3 + 0] = qx[j];
    pos_s[slot * 3 + 1] = qy[j];
    pos_s[slot * 3 + 2] = qz[j];
    ids_s[slot] = tid * PPT + j;
  }
}

// key of owned point j: (origidx<<13) | storageidx — lex tie-break == jnp.argmax
#define KEYOF(j) (((((idp[(j) >> 1] >> (((j) & 1) * 16)) & 0xffff)) << 13) | (tid * PPT + (j)))

#define PAIR2(v1, k1, v2, k2, a, ka, b, kb) { bool t_ = LEXGT(b, kb, a, ka); \
  v1 = t_ ? (b) : (a); k1 = t_ ? (kb) : (ka); v2 = t_ ? (a) : (b); k2 = t_ ? (ka) : (kb); }

#define MERGE22(v1, k1, v2, k2, w1, l1, w2, l2) { \
  bool t_ = LEXGT(w1, l1, v1, k1); \
  float lv_ = t_ ? (v1) : (w1); int lk_ = t_ ? (k1) : (l1); \
  float ov_ = t_ ? (w2) : (v2); int ok_ = t_ ? (l2) : (k2); \
  v1 = t_ ? (w1) : (v1); k1 = t_ ? (l1) : (k1); \
  bool u_ = LEXGT(lv_, lk_, ov_, ok_); \
  v2 = u_ ? lv_ : ov_; k2 = u_ ? lk_ : ok_; }

// thread-local top2 over the 8 owned (dd, key) pairs
#define RESCAN2() { \
  float A1, B1, C1, D1, A2, B2, C2, D2; int Ak, Bk, Ck, Dk, Ak2, Bk2, Ck2, Dk2; \
  PAIR2(A1, Ak, A2, Ak2, dd[0], KEYOF(0), dd[1], KEYOF(1)) \
  PAIR2(B1, Bk, B2, Bk2, dd[2], KEYOF(2), dd[3], KEYOF(3)) \
  PAIR2(C1, Ck, C2, Ck2, dd[4], KEYOF(4), dd[5], KEYOF(5)) \
  PAIR2(D1, Dk, D2, Dk2, dd[6], KEYOF(6), dd[7], KEYOF(7)) \
  MERGE22(A1, Ak, A2, Ak2, B1, Bk, B2, Bk2) \
  MERGE22(C1, Ck, C2, Ck2, D1, Dk, D2, Dk2) \
  MERGE22(A1, Ak, A2, Ak2, C1, Ck, C2, Ck2) \
  bv = A1; bkey = Ak; bv2 = A2; bk2 = Ak2; }

// wave top-2 merge + publish to slot set sn
#define WAVE_PUBLISH(sn) { \
  float rv1 = bv; int rk1 = bkey; float rv2 = bv2; int rk2 = bk2; \
  dpp_top2<0x111>(rv1, rk1, rv2, rk2); dpp_top2<0x112>(rv1, rk1, rv2, rk2); \
  dpp_top2<0x114>(rv1, rk1, rv2, rk2); dpp_top2<0x118>(rv1, rk1, rv2, rk2); \
  dpp_top2<0x142>(rv1, rk1, rv2, rk2); dpp_top2<0x143>(rv1, rk1, rv2, rk2); \
  int wk1u = __builtin_amdgcn_readlane(rk1, 63); \
  int wv2u = __builtin_amdgcn_readlane(__float_as_int(rv2), 63); \
  int wk2u = __builtin_amdgcn_readlane(rk2, 63); \
  if (bkey == wk1u) { \
    const int jj_ = bkey & 7; \
    float sx_ = x[0], sy_ = y[0], sz_ = z[0]; \
    _Pragma("unroll") \
    for (int j = 0; j < PPT; ++j) \
      if (j == jj_) { sx_ = x[j]; sy_ = y[j]; sz_ = z[j]; } \
    sC[sn][0][wave] = __float_as_int(bv); \
    sC[sn][1][wave] = bkey; \
    sC[sn][2][wave] = __float_as_int(sx_); \
    sC[sn][3][wave] = __float_as_int(sy_); \
    sC[sn][4][wave] = __float_as_int(sz_); \
    sC[sn][5][wave] = wv2u; \
    sC[sn][6][wave] = wk2u; \
  } }

// ---------------------------------------------------------------------------
// FPS with exact batched lookahead: per barrier-round, extract up to 4
// provably-correct consecutive selections from the 16 per-wave champions.
// Acceptance (all in the reference's own f32 sqrt/eucl2 arithmetic):
//   - candidate lex-beats every accepted wave's (stale, valid-upper-bound)
//     runner-up,
//   - dist(candidate, each previously-accepted) >= its value (value provably
//     unchanged by the batch),
//   - stop the batch when any pool champion gets wounded (conservative).
// A>=1 always => progress; A=1 degenerates to the classic exact iteration.
// ---------------------------------------------------------------------------
__global__ __launch_bounds__(FT) void fps_kernel(const float* __restrict__ pos,
                                                 const float* __restrict__ pos_s,
                                                 const int* __restrict__ ids_s,
                                                 float* __restrict__ pos_out) {
  __shared__ int sC[2][7][16];   // [parity][field: v1,k1,x,y,z,v2,k2][wave]
  __shared__ unsigned char flag[FPS_N];
  __shared__ int sc[FT];
  const int tid = threadIdx.x, lane = tid & 63, wave = tid >> 6;

  { int* f4 = (int*)flag; f4[tid * 2] = 0; f4[tid * 2 + 1] = 0; }

  float x[PPT], y[PPT], z[PPT], d2[PPT], dd[PPT];
  int idp[PPT / 2];
  {
    const float4* p4 = (const float4*)pos_s + tid * 6;
    float4 a0 = p4[0], a1 = p4[1], a2 = p4[2], a3 = p4[3], a4 = p4[4], a5 = p4[5];
    x[0]=a0.x; y[0]=a0.y; z[0]=a0.z;
    x[1]=a0.w; y[1]=a1.x; z[1]=a1.y;
    x[2]=a1.z; y[2]=a1.w; z[2]=a2.x;
    x[3]=a2.y; y[3]=a2.z; z[3]=a2.w;
    x[4]=a3.x; y[4]=a3.y; z[4]=a3.z;
    x[5]=a3.w; y[5]=a4.x; z[5]=a4.y;
    x[6]=a4.z; y[6]=a4.w; z[6]=a5.x;
    x[7]=a5.y; y[7]=a5.z; z[7]=a5.w;
    const int4* i4 = (const int4*)ids_s + tid * 2;
    int4 b0 = i4[0], b1 = i4[1];
    idp[0] = (b0.x & 0xffff) | (b0.y << 16);
    idp[1] = (b0.z & 0xffff) | (b0.w << 16);
    idp[2] = (b1.x & 0xffff) | (b1.y << 16);
    idp[3] = (b1.z & 0xffff) | (b1.w << 16);
  }

  const float p0x = pos[0], p0y = pos[1], p0z = pos[2];
#pragma unroll
  for (int j = 0; j < PPT; ++j) {
    float s = eucl2(x[j], y[j], z[j], p0x, p0y, p0z);
    int oid = (idp[j >> 1] >> ((j & 1) * 16)) & 0xffff;
    if (oid == 0) { d2[j] = NEGINF; dd[j] = NEGINF; }
    else          { d2[j] = s;      dd[j] = sqrtf(s); }
  }
  float bnx = x[0], bny = y[0], bnz = z[0], bxx = x[0], bxy = y[0], bxz = z[0];
#pragma unroll
  for (int j = 1; j < PPT; ++j) {
    bnx = fminf(bnx, x[j]); bny = fminf(bny, y[j]); bnz = fminf(bnz, z[j]);
    bxx = fmaxf(bxx, x[j]); bxy = fmaxf(bxy, y[j]); bxz = fmaxf(bxz, z[j]);
  }
  if (tid == 0) flag[0] = 1;

  float bv, bv2; int bkey, bk2; bool chb;
  RESCAN2();
  chb = false;
  WAVE_PUBLISH(0);
  __syncthreads();

  int sel = 0, rp = 0;
  while (sel < FPS_K - 1) {
    const int s16 = lane & 15;
    const float c_v1 = __int_as_float(sC[rp][0][s16]);
    const int   c_k1 = sC[rp][1][s16];
    const float c_x  = __int_as_float(sC[rp][2][s16]);
    const float c_y  = __int_as_float(sC[rp][3][s16]);
    const float c_z  = __int_as_float(sC[rp][4][s16]);
    const float c_v2 = __int_as_float(sC[rp][5][s16]);
    const int   c_k2 = sC[rp][6][s16];

    bool elig = true, cont = true;
    int A = 0;
    const int cap = FPS_K - 1 - sel;
    float mu_v = NEGINF; int mu_k = KMAX;
    float ax0=0, ay0=0, az0=0, ax1=0, ay1=0, az1=0, ax2=0, ay2=0, az2=0, ax3=0, ay3=0, az3=0;

#define BSTEP(AXT, AYT, AZT, DISTCHK) \
    if (cont) { \
      float ev = elig ? c_v1 : NEGINF; int ek = elig ? c_k1 : KMAX; \
      float wx = c_x, wy = c_y, wz = c_z, wv2 = c_v2; int wk2 = c_k2; \
      dpp_sel7<0xB1>(ev, ek, wx, wy, wz, wv2, wk2); \
      dpp_sel7<0x4E>(ev, ek, wx, wy, wz, wv2, wk2); \
      dpp_sel7<0x124>(ev, ek, wx, wy, wz, wv2, wk2); \
      dpp_sel7<0x128>(ev, ek, wx, wy, wz, wv2, wk2); \
      bool good = (ev != NEGINF) && LEXGT(ev, ek, mu_v, mu_k); \
      DISTCHK \
      if (good) { \
        AXT = wx; AYT = wy; AZT = wz; \
        if (LEXGT(wv2, wk2, mu_v, mu_k)) { mu_v = wv2; mu_k = wk2; } \
        const int stor = ek & 8191; \
        if ((stor >> 3) == tid) { \
          const int jj = stor & 7; \
          _Pragma("unroll") \
          for (int j = 0; j < PPT; ++j) \
            if (j == jj) { d2[j] = NEGINF; dd[j] = NEGINF; } \
          chb = true; \
        } \
        if (tid == 0) flag[ek >> 13] = 1; \
        bool killed = false; \
        if (c_k1 == ek) elig = false; \
        else if (elig) { \
          float dm = sqrtf(eucl2(c_x, c_y, c_z, wx, wy, wz)); \
          if (dm < c_v1) { elig = false; killed = true; } \
        } \
        unsigned long long kb = __ballot(killed ? 1 : 0); \
        ++A; \
        cont = (kb == 0ULL) && (A < cap) && (A < 4); \
      } else cont = false; \
    }

    BSTEP(ax0, ay0, az0, )
    BSTEP(ax1, ay1, az1, good = good && (sqrtf(eucl2(wx, wy, wz, ax0, ay0, az0)) >= ev);)
    BSTEP(ax2, ay2, az2, good = good && (sqrtf(eucl2(wx, wy, wz, ax0, ay0, az0)) >= ev)
                               && (sqrtf(eucl2(wx, wy, wz, ax1, ay1, az1)) >= ev);)
    BSTEP(ax3, ay3, az3, good = good && (sqrtf(eucl2(wx, wy, wz, ax0, ay0, az0)) >= ev)
                               && (sqrtf(eucl2(wx, wy, wz, ax1, ay1, az1)) >= ev)
                               && (sqrtf(eucl2(wx, wy, wz, ax2, ay2, az2)) >= ev);)
#undef BSTEP

    // ---- combined bbox-gated update over the A accepted centers ----
    unsigned cm = 0;
    const float tub = (bv == NEGINF) ? NEGINF : bv * bv;
#define UPDC(T, AXT, AYT, AZT) \
    if (A > T) { \
      float cx = fminf(fmaxf(AXT, bnx), bxx); \
      float cy = fminf(fmaxf(AYT, bny), bxy); \
      float cz = fminf(fmaxf(AZT, bnz), bxz); \
      float ddx = AXT - cx, ddy = AYT - cy, ddz = AZT - cz; \
      float bd2 = ddx * ddx + ddy * ddy + ddz * ddz; \
      if (bd2 * 0.999f < tub) { \
        _Pragma("unroll") \
        for (int j = 0; j < PPT; ++j) { \
          float s = eucl2(x[j], y[j], z[j], AXT, AYT, AZT); \
          if (s < d2[j]) { d2[j] = s; cm |= (1u << j); } \
        } \
      } \
    }
    UPDC(0, ax0, ay0, az0)
    UPDC(1, ax1, ay1, az1)
    UPDC(2, ax2, ay2, az2)
    UPDC(3, ax3, ay3, az3)
#undef UPDC
    if (cm) {
#pragma unroll
      for (int j = 0; j < PPT; ++j)
        if ((cm >> j) & 1) dd[j] = sqrtf(d2[j]);
      if ((cm >> (bkey & 7)) & 1) chb = true;
    }

    const int pn = rp ^ 1;
    unsigned long long any = __ballot(chb ? 1 : 0);
    if (any) {
      if (chb) { RESCAN2(); chb = false; }
      WAVE_PUBLISH(pn);
    } else {
      if (lane < 7) sC[pn][lane][wave] = sC[rp][lane][wave];
    }
    sel += A;
    rp = pn;
    __syncthreads();
  }

  // ---- emit selected points in ascending ORIGINAL index order ----
  const int* fI = (const int*)flag;
  int w0 = fI[tid * 2], w1 = fI[tid * 2 + 1];
  int cnt = __popc(w0) + __popc(w1);
  sc[tid] = cnt;
  __syncthreads();
  for (int off = 1; off < FT; off <<= 1) {
    int u = (tid >= off) ? sc[tid - off] : 0;
    __syncthreads();
    sc[tid] += u;
    __syncthreads();
  }
  int r = sc[tid] - cnt;
#pragma unroll
  for (int j = 0; j < PPT; ++j) {
    int w = (j < 4) ? w0 : w1;
    if ((w >> ((j & 3) * 8)) & 1) {
      int oi = tid * PPT + j;
      pos_out[r * 3 + 0] = pos[oi * 3 + 0];
      pos_out[r * 3 + 1] = pos[oi * 3 + 1];
      pos_out[r * 3 + 2] = pos[oi * 3 + 2];
      ++r;
    }
  }
}

// ---------------------------------------------------------------------------
// W^T (256x256) into scratch (start of mask region; overwritten later).
// ---------------------------------------------------------------------------
__global__ __launch_bounds__(256) void wt_kernel(const float* __restrict__ W,
                                                 float* __restrict__ WT) {
  int i = blockIdx.x * 256 + threadIdx.x;
  int c = i >> 8, cp = i & 255;
  WT[i] = W[cp * 256 + c];
}

// ---------------------------------------------------------------------------
// Fused sparse aggregation + Linear. One block per node m.
// ---------------------------------------------------------------------------
__global__ __launch_bounds__(256) void agg_linear_kernel(
    const float* __restrict__ h, const float* __restrict__ pos,
    const float* __restrict__ nodepos, const float* __restrict__ WT,
    const float* __restrict__ bias, float* __restrict__ embed, float sb) {
  const int m = blockIdx.x;
  const int tid = threadIdx.x;
  const int lane = tid & 63, wave = tid >> 6;
  const float nx = nodepos[m * 3 + 0];
  const float ny = nodepos[m * 3 + 1];
  const float nz = nodepos[m * 3 + 2];
  const float4* h4 = (const float4*)h;

  float4 acc = make_float4(0.f, 0.f, 0.f, 0.f);
  const int base0 = wave * (FPS_N / 4);
  for (int base = base0; base < base0 + (FPS_N / 4); base += 64) {
    int n = base + lane;
    float px = pos[n * 3 + 0], py = pos[n * 3 + 1], pz = pos[n * 3 + 2];
    unsigned long long mb = __ballot((p3sum(px, py, pz, nx, ny, nz) <= sb) ? 1 : 0);
    while (mb) {
      int b = __ffsll(mb) - 1;
      mb &= (mb - 1);
      float4 hv = h4[(size_t)(base + b) * 64 + lane];
      acc.x += hv.x; acc.y += hv.y; acc.z += hv.z; acc.w += hv.w;
    }
  }

  __shared__ float lacc[4][256];
  lacc[wave][lane * 4 + 0] = acc.x;
  lacc[wave][lane * 4 + 1] = acc.y;
  lacc[wave][lane * 4 + 2] = acc.z;
  lacc[wave][lane * 4 + 3] = acc.w;
  __syncthreads();
  __shared__ float aggrow[256];
  float aggv = ((lacc[0][tid] + lacc[1][tid]) + lacc[2][tid]) + lacc[3][tid];
  aggrow[tid] = aggv;
  __syncthreads();

  float o = bias[tid];
#pragma unroll 8
  for (int c = 0; c < 256; ++c)
    o = fmaf(aggrow[c], WT[c * 256 + tid], o);
  embed[(size_t)m * 256 + tid] = o;
}

// ---------------------------------------------------------------------------
// Mask output: mask[n][m] = (sum|d|^3 <= sb) ? 1.0 : 0.0   (8192 x 4096 f32)
// ---------------------------------------------------------------------------
__global__ __launch_bounds__(256) void mask_kernel(const float* __restrict__ pos,
                                                   const float* __restrict__ nodepos,
                                                   float* __restrict__ maskout,
                                                   float sb) {
  int n  = blockIdx.y;
  int m0 = (blockIdx.x * 256 + threadIdx.x) * 4;
  float x = pos[n * 3 + 0], y = pos[n * 3 + 1], z = pos[n * 3 + 2];
  const float4* np4 = (const float4*)(nodepos + (size_t)m0 * 3);
  float4 a = np4[0], bq = np4[1], cq = np4[2];
  float4 r;
  r.x = (p3sum(x, y, z, a.x,  a.y,  a.z)  <= sb) ? 1.0f : 0.0f;
  r.y = (p3sum(x, y, z, a.w,  bq.x, bq.y) <= sb) ? 1.0f : 0.0f;
  r.z = (p3sum(x, y, z, bq.z, bq.w, cq.x) <= sb) ? 1.0f : 0.0f;
  r.w = (p3sum(x, y, z, cq.y, cq.z, cq.w) <= sb) ? 1.0f : 0.0f;
  *(float4*)(maskout + (size_t)n * FPS_K + m0) = r;
}

extern "C" void kernel_launch(void* const* d_in, const int* in_sizes, int n_in,
                              void* d_out, int out_size, void* d_ws, size_t ws_size,
                              hipStream_t stream) {
  (void)in_sizes; (void)n_in; (void)out_size; (void)d_ws; (void)ws_size;
  const float* h   = (const float*)d_in[0];
  const float* pos = (const float*)d_in[1];
  const float* W   = (const float*)d_in[2];
  const float* b   = (const float*)d_in[3];

  float* out     = (float*)d_out;
  float* embed   = out;                                   // 4096*256
  float* pos_out = out + (size_t)FPS_K * CS;              // 4096*3
  float* mask    = pos_out + (size_t)FPS_K * 3;           // 8192*4096
  float* WT      = mask;                                  // scratch (overwritten)
  float* pos_s   = mask + (1 << 21);                      // sorted coords scratch
  int*   ids_s   = (int*)(pos_s + 3 * FPS_N);             // sorted->orig idx

  // Threshold model: ref mask true  <=>  cbrt_f32(s) < 0.3f
  const float  t    = 0.3f;
  const float  ulpv = nextafterf(t, 1.0f) - t;
  const double rmid = (double)t - (double)ulpv * 0.5;
  const double C    = rmid * rmid * rmid;
  float sb = (float)C;
  if (!((double)sb < C)) sb = nextafterf(sb, 0.0f);

  hipLaunchKernelGGL(bin_kernel, dim3(1), dim3(FT), 0, stream, pos, pos_s, ids_s);
  hipLaunchKernelGGL(fps_kernel, dim3(1), dim3(FT), 0, stream, pos, pos_s, ids_s, pos_out);
  hipLaunchKernelGGL(wt_kernel, dim3(256), dim3(256), 0, stream, W, WT);
  hipLaunchKernelGGL(agg_linear_kernel, dim3(FPS_K), dim3(256), 0, stream,
                     h, pos, pos_out, WT, b, embed, sb);
  hipLaunchKernelGGL(mask_kernel, dim3(4, FPS_N), dim3(256), 0, stream,
                     pos, pos_out, mask, sb);
}